// Round 2
// baseline (1392.359 us; speedup 1.0000x reference)
//
#include <hip/hip_runtime.h>
#include <hip/hip_bf16.h>
#include <stdint.h>

// Problem constants (T, B, N, D) = (4, 16, 1024, 512); M = B*N
#define T_ 4
#define M_ 16384
#define D_ 512
#define R_ (T_ * M_)    // 65536 rows total
#define EPS_TRIG 1e-4f  // ~5 sigma of the bf16-split accumulation noise

typedef short bf16x8 __attribute__((ext_vector_type(8)));   // 8 bf16 (4 VGPRs)
typedef float f32x4  __attribute__((ext_vector_type(4)));
typedef unsigned short us8 __attribute__((ext_vector_type(8)));

// x = hi + lo + residual, |residual| <= 2^-17 |x|.
// hi: truncation (bit-chop); lo: RNE of the exact fp32 residual.
static __device__ __forceinline__ void split2bf16(float x, unsigned short& h, unsigned short& l) {
    unsigned int u = __float_as_uint(x);
    h = (unsigned short)(u >> 16);
    float r = x - __uint_as_float(u & 0xFFFF0000u);   // exact
    unsigned int v = __float_as_uint(r);
    l = (unsigned short)((v + 0x7FFFu + ((v >> 16) & 1u)) >> 16);
}

// Async global->LDS, 16 B per lane. LDS dest = wave-uniform base + lane*16.
static __device__ __forceinline__ void gload_lds16(const void* g, void* l) {
    __builtin_amdgcn_global_load_lds(
        (const __attribute__((address_space(1))) unsigned int*)g,
        (__attribute__((address_space(3))) unsigned int*)l,
        16, 0, 0);
}

// ---------------------------------------------------------------------------
// LEGACY kernel 0: one-shot W split -> Wh, Wl (row-major), fallback path only.
// ---------------------------------------------------------------------------
__global__ __launch_bounds__(256) void split_w_kernel(
    const float* __restrict__ Wq, const float* __restrict__ Wk, const float* __restrict__ Wv,
    unsigned short* __restrict__ Wh, unsigned short* __restrict__ Wl)
{
    const int idx4 = blockIdx.x * 256 + threadIdx.x;  // float4 index, < 196608
    const int flat = idx4 * 4;
    const int z    = flat >> 18;                      // 262144 elements per matrix
    const int off  = flat & 262143;
    const float* src = (z == 0) ? Wq : (z == 1) ? Wk : Wv;
    float4 v = *reinterpret_cast<const float4*>(src + off);
    ushort4 h, l;
    split2bf16(v.x, h.x, l.x);
    split2bf16(v.y, h.y, l.y);
    split2bf16(v.z, h.z, l.z);
    split2bf16(v.w, h.w, l.w);
    *reinterpret_cast<ushort4*>(Wh + flat) = h;
    *reinterpret_cast<ushort4*>(Wl + flat) = l;
}

// ---------------------------------------------------------------------------
// FAST kernel 0a: W split -> TILED layout for global_load_lds staging.
// Wtiled byte layout: [bd(8)][kbi(16)][wj(24)][dd(64)][16B], where
// wj = (hl*4+g)*3+z encodes (hl, k-granule g, z), dd = W row within d-slice.
// One thread per 16-B granule (8 bf16). Writes fully coalesced.
// ---------------------------------------------------------------------------
__global__ __launch_bounds__(256) void split_w_tiled(
    const float* __restrict__ Wq, const float* __restrict__ Wk, const float* __restrict__ Wv,
    unsigned short* __restrict__ Wt)
{
    const int flat = blockIdx.x * 256 + threadIdx.x;  // 0..196607
    const int dd   = flat & 63;
    const int rest = flat >> 6;        // = bk*24 + wj
    const int wj   = rest % 24;
    const int bk   = rest / 24;        // bd*16 + kbi
    const int kbi  = bk & 15;
    const int bd   = bk >> 4;
    const int z    = wj % 3;
    const int hg   = wj / 3;
    const int hl   = hg >> 2;
    const int g    = hg & 3;

    const float* src = ((z == 0) ? Wq : (z == 1) ? Wk : Wv)
                       + (size_t)(bd * 64 + dd) * D_ + kbi * 32 + g * 8;
    float4 a = *reinterpret_cast<const float4*>(src);
    float4 b = *reinterpret_cast<const float4*>(src + 4);

    us8 hv, lv;
    unsigned short hh, ll;
    split2bf16(a.x, hh, ll); hv[0] = hh; lv[0] = ll;
    split2bf16(a.y, hh, ll); hv[1] = hh; lv[1] = ll;
    split2bf16(a.z, hh, ll); hv[2] = hh; lv[2] = ll;
    split2bf16(a.w, hh, ll); hv[3] = hh; lv[3] = ll;
    split2bf16(b.x, hh, ll); hv[4] = hh; lv[4] = ll;
    split2bf16(b.y, hh, ll); hv[5] = hh; lv[5] = ll;
    split2bf16(b.z, hh, ll); hv[6] = hh; lv[6] = ll;
    split2bf16(b.w, hh, ll); hv[7] = hh; lv[7] = ll;

    *reinterpret_cast<us8*>((char*)Wt + (size_t)flat * 16) = hl ? lv : hv;
}

// ---------------------------------------------------------------------------
// FAST kernel 0b: X split -> TILED layout.
// Xtiled byte layout: [bm(512)][kbi(16)][hl(2)][g(4)][row(128)][16B],
// row = t*32 + mm. Each thread handles one (g,row) granule, both hl slabs.
// Writes coalesced (row fastest); reads stride-2KB, L2-absorbed (one-shot).
// ---------------------------------------------------------------------------
__global__ __launch_bounds__(256) void split_x_tiled(
    const float* __restrict__ X, unsigned short* __restrict__ Xt)
{
    const int flat = blockIdx.x * 256 + threadIdx.x;  // 0..4194303
    const int row  = flat & 127;
    const int g    = (flat >> 7) & 3;
    const int bk   = flat >> 9;        // bm*16 + kbi
    const int kbi  = bk & 15;
    const int bm   = bk >> 4;
    const int t    = row >> 5;
    const int mm   = row & 31;

    const float* src = X + (size_t)(t * M_ + bm * 32 + mm) * D_ + kbi * 32 + g * 8;
    float4 a = *reinterpret_cast<const float4*>(src);
    float4 b = *reinterpret_cast<const float4*>(src + 4);

    us8 hv, lv;
    unsigned short hh, ll;
    split2bf16(a.x, hh, ll); hv[0] = hh; lv[0] = ll;
    split2bf16(a.y, hh, ll); hv[1] = hh; lv[1] = ll;
    split2bf16(a.z, hh, ll); hv[2] = hh; lv[2] = ll;
    split2bf16(a.w, hh, ll); hv[3] = hh; lv[3] = ll;
    split2bf16(b.x, hh, ll); hv[4] = hh; lv[4] = ll;
    split2bf16(b.y, hh, ll); hv[5] = hh; lv[5] = ll;
    split2bf16(b.z, hh, ll); hv[6] = hh; lv[6] = ll;
    split2bf16(b.w, hh, ll); hv[7] = hh; lv[7] = ll;

    char* chunk = (char*)Xt + (size_t)bk * 16384;
    const int off = g * 2048 + row * 16;
    *reinterpret_cast<us8*>(chunk + off)        = hv;   // hl = 0 (hi)
    *reinterpret_cast<us8*>(chunk + 8192 + off) = lv;   // hl = 1 (lo)
}

// ---------------------------------------------------------------------------
// Shared epilogue: LIF (fp32 + exact-f64 fixup) + attn = q * cumsum(k & v)
// ---------------------------------------------------------------------------
static __device__ __forceinline__ void lif_attn_epilogue(
    f32x4 (&acc)[2][3][T_], const float* __restrict__ X,
    const float* __restrict__ Wq, const float* __restrict__ Wk, const float* __restrict__ Wv,
    unsigned char* __restrict__ attn, int bd, int bm, int wsub, int la, int lq)
{
    const int d = bd * 64 + wsub * 16 + la;
    #pragma unroll
    for (int s = 0; s < 2; s++)
        #pragma unroll
        for (int i = 0; i < 4; i++) {
            const int m = bm * 32 + s * 16 + lq * 4 + i;
            int sp[3][T_];
            #pragma unroll
            for (int z = 0; z < 3; z++) {
                float mem = 0.f;
                bool risky = false;
                #pragma unroll
                for (int t = 0; t < T_; t++) {
                    mem = 0.9f * mem + acc[s][z][t][i];
                    risky |= (fabsf(mem - 1.0f) < EPS_TRIG);
                    const int sb = (mem >= 1.0f) ? 1 : 0;
                    sp[z][t] = sb;
                    mem -= (float)sb;
                }
                if (risky) {
                    const float* Wrow = ((z == 0) ? Wq : ((z == 1) ? Wk : Wv)) + (size_t)d * D_;
                    double pre[T_];
                    #pragma unroll
                    for (int t = 0; t < T_; t++) {
                        const float* xrow = X + (size_t)(t * M_ + m) * D_;
                        double s0 = 0.0, s1 = 0.0, s2 = 0.0, s3 = 0.0;
                        for (int k = 0; k < D_; k += 4) {
                            s0 += (double)xrow[k + 0] * (double)Wrow[k + 0];
                            s1 += (double)xrow[k + 1] * (double)Wrow[k + 1];
                            s2 += (double)xrow[k + 2] * (double)Wrow[k + 2];
                            s3 += (double)xrow[k + 3] * (double)Wrow[k + 3];
                        }
                        pre[t] = (s0 + s1) + (s2 + s3);
                    }
                    double dm = 0.0;
                    #pragma unroll
                    for (int t = 0; t < T_; t++) {
                        dm = 0.9 * dm + pre[t];
                        const int sb = (dm >= 1.0) ? 1 : 0;
                        sp[z][t] = sb;
                        dm -= (double)sb;
                    }
                }
            }
            int ctx = 0;
            #pragma unroll
            for (int t = 0; t < T_; t++) {
                ctx += sp[1][t] & sp[2][t];
                attn[(size_t)(t * M_ + m) * D_ + d] = (unsigned char)(sp[0][t] ? ctx : 0);
            }
        }
}

// ---------------------------------------------------------------------------
// FAST kernel 1: projection via bf16 MFMA with pure global_load_lds staging.
//
// Both operands are pre-split bf16 in workspace, stored in LDS-tile byte
// order, so each wave stages with contiguous coalesced 1024-B
// global_load_lds_dwordx4 ops: NO staging VALU, NO VGPR round-trip, and a
// conflict-free k-granule-major LDS layout ([hl][g][row][16B]: frag-read
// banks = (row*4+j) mod 32, exactly 8 words/bank = balanced minimum).
// MFMA operand values are bit-identical to the legacy kernel.
// Tile: 32m x 64d(x3z) x 4t, K-step 32, 4 waves. LDS 40 KB.
// ---------------------------------------------------------------------------
__global__ __launch_bounds__(256) void proj_lif_attn_mfma_t(
    const float* __restrict__ X,
    const float* __restrict__ Wq, const float* __restrict__ Wk, const float* __restrict__ Wv,
    const unsigned short* __restrict__ XtS, const unsigned short* __restrict__ WtS,
    unsigned char* __restrict__ attn)
{
    __shared__ unsigned short Xs[8192];    // [hl(2)][g(4)][row(128)][8] 16 KB
    __shared__ unsigned short Ws[12288];   // [hl(2)][g(4)][z*64+dd(192)][8] 24 KB

    const int tid  = threadIdx.x;
    const int lane = tid & 63;
    const int wsub = tid >> 6;     // 0..3 -> 16-d subtile
    const int la   = lane & 15;
    const int lq   = lane >> 4;
    const int bd   = blockIdx.x;   // 0..7   (64 d per block)
    const int bm   = blockIdx.y;   // 0..511 (32 m per block)

    f32x4 acc[2][3][T_];
    #pragma unroll
    for (int s = 0; s < 2; s++)
        #pragma unroll
        for (int z = 0; z < 3; z++)
            #pragma unroll
            for (int t = 0; t < T_; t++)
                acc[s][z][t] = (f32x4){0.f, 0.f, 0.f, 0.f};

    // Per-wave staging: X slabs wi = wsub*4 + i (16 x 1024 B), W slabs
    // wj = wsub*6 + j (24 x 1024 B). Source chunk interior is byte-identical
    // to the LDS layout, so src = chunk + slab*1024 + lane*16.
    const char* xsrc0 = (const char*)XtS + ((size_t)(bm * 16)) * 16384 + (wsub * 4) * 1024 + lane * 16;
    const char* wsrc0 = (const char*)WtS + ((size_t)(bd * 16)) * 24576 + (wsub * 6) * 1024 + lane * 16;
    char* xdst = (char*)Xs + (wsub * 4) * 1024;
    char* wdst = (char*)Ws + (wsub * 6) * 1024;

    for (int kbi = 0; kbi < 16; kbi++) {
        const char* xs = xsrc0 + (size_t)kbi * 16384;
        const char* ws = wsrc0 + (size_t)kbi * 24576;
        #pragma unroll
        for (int i = 0; i < 4; i++)
            gload_lds16(xs + i * 1024, xdst + i * 1024);
        #pragma unroll
        for (int j = 0; j < 6; j++)
            gload_lds16(ws + j * 1024, wdst + j * 1024);
        __syncthreads();   // compiler inserts s_waitcnt vmcnt(0) before barrier

        bf16x8 bh[3], bl[3];
        #pragma unroll
        for (int z = 0; z < 3; z++) {
            const int wbase = lq * 1536 + z * 512 + wsub * 128 + la * 8;
            bh[z] = *reinterpret_cast<const bf16x8*>(&Ws[wbase]);
            bl[z] = *reinterpret_cast<const bf16x8*>(&Ws[6144 + wbase]);
        }
        #pragma unroll
        for (int s = 0; s < 2; s++)
            #pragma unroll
            for (int t = 0; t < T_; t++) {
                const int abase = lq * 1024 + (t * 32 + s * 16 + la) * 8;
                bf16x8 ah = *reinterpret_cast<const bf16x8*>(&Xs[abase]);
                bf16x8 al = *reinterpret_cast<const bf16x8*>(&Xs[4096 + abase]);
                #pragma unroll
                for (int z = 0; z < 3; z++) {
                    acc[s][z][t] = __builtin_amdgcn_mfma_f32_16x16x32_bf16(ah, bh[z], acc[s][z][t], 0, 0, 0);
                    acc[s][z][t] = __builtin_amdgcn_mfma_f32_16x16x32_bf16(ah, bl[z], acc[s][z][t], 0, 0, 0);
                    acc[s][z][t] = __builtin_amdgcn_mfma_f32_16x16x32_bf16(al, bh[z], acc[s][z][t], 0, 0, 0);
                }
            }
        __syncthreads();
    }

    lif_attn_epilogue(acc, X, Wq, Wk, Wv, attn, bd, bm, wsub, la, lq);
}

// ---------------------------------------------------------------------------
// LEGACY kernel 1 (round-1, fallback when workspace too small).
// ---------------------------------------------------------------------------
__global__ __launch_bounds__(256) void proj_lif_attn_mfma(
    const float* __restrict__ X,
    const float* __restrict__ Wq, const float* __restrict__ Wk, const float* __restrict__ Wv,
    const unsigned short* __restrict__ WhS, const unsigned short* __restrict__ WlS,
    unsigned char* __restrict__ attn)
{
    __shared__ unsigned short XsH[128 * 40];
    __shared__ unsigned short XsL[128 * 40];
    __shared__ unsigned short WsH[192 * 40];
    __shared__ unsigned short WsL[192 * 40];

    const int tid  = threadIdx.x;
    const int lane = tid & 63;
    const int wsub = tid >> 6;
    const int la   = lane & 15;
    const int lq   = lane >> 4;
    const int bd   = blockIdx.x;
    const int bm   = blockIdx.y;

    f32x4 acc[2][3][T_];
    #pragma unroll
    for (int s = 0; s < 2; s++)
        #pragma unroll
        for (int z = 0; z < 3; z++)
            #pragma unroll
            for (int t = 0; t < T_; t++)
                acc[s][z][t] = (f32x4){0.f, 0.f, 0.f, 0.f};

    for (int kb = 0; kb < D_; kb += 32) {
        #pragma unroll
        for (int i = 0; i < 4; i++) {
            const int j   = tid + i * 256;
            const int row = j >> 3;
            const int kq  = (j & 7) * 4;
            const int t   = row >> 5;
            const int mm  = row & 31;
            float4 xv = *reinterpret_cast<const float4*>(
                X + ((size_t)(t * M_ + bm * 32 + mm) * D_ + kb + kq));
            ushort4 h, l;
            split2bf16(xv.x, h.x, l.x);
            split2bf16(xv.y, h.y, l.y);
            split2bf16(xv.z, h.z, l.z);
            split2bf16(xv.w, h.w, l.w);
            *reinterpret_cast<ushort4*>(&XsH[row * 40 + kq]) = h;
            *reinterpret_cast<ushort4*>(&XsL[row * 40 + kq]) = l;
        }
        {
            const int wd  = tid >> 2;
            const int wkg = tid & 3;
            #pragma unroll
            for (int z = 0; z < 3; z++) {
                const size_t goff = (size_t)(z * D_ + bd * 64 + wd) * D_ + kb + wkg * 8;
                int4 hv = *reinterpret_cast<const int4*>(WhS + goff);
                int4 lv = *reinterpret_cast<const int4*>(WlS + goff);
                *reinterpret_cast<int4*>(&WsH[(z * 64 + wd) * 40 + wkg * 8]) = hv;
                *reinterpret_cast<int4*>(&WsL[(z * 64 + wd) * 40 + wkg * 8]) = lv;
            }
        }
        __syncthreads();

        bf16x8 bh[3], bl[3];
        #pragma unroll
        for (int z = 0; z < 3; z++) {
            const int brow = (z * 64 + wsub * 16 + la) * 40 + lq * 8;
            bh[z] = *reinterpret_cast<const bf16x8*>(&WsH[brow]);
            bl[z] = *reinterpret_cast<const bf16x8*>(&WsL[brow]);
        }
        #pragma unroll
        for (int s = 0; s < 2; s++)
            #pragma unroll
            for (int t = 0; t < T_; t++) {
                const int arow = (t * 32 + s * 16 + la) * 40 + lq * 8;
                bf16x8 ah = *reinterpret_cast<const bf16x8*>(&XsH[arow]);
                bf16x8 al = *reinterpret_cast<const bf16x8*>(&XsL[arow]);
                #pragma unroll
                for (int z = 0; z < 3; z++) {
                    acc[s][z][t] = __builtin_amdgcn_mfma_f32_16x16x32_bf16(ah, bh[z], acc[s][z][t], 0, 0, 0);
                    acc[s][z][t] = __builtin_amdgcn_mfma_f32_16x16x32_bf16(ah, bl[z], acc[s][z][t], 0, 0, 0);
                    acc[s][z][t] = __builtin_amdgcn_mfma_f32_16x16x32_bf16(al, bh[z], acc[s][z][t], 0, 0, 0);
                }
            }
        __syncthreads();
    }

    lif_attn_epilogue(acc, X, Wq, Wk, Wv, attn, bd, bm, wsub, la, lq);
}

// ---------------------------------------------------------------------------
// Kernel 2: out = attn @ Wp^T + bp via bf16 MFMA (unchanged, known good).
// ---------------------------------------------------------------------------
__global__ __launch_bounds__(256) void attn_out_gemm_mfma(
    const unsigned char* __restrict__ A,    // (R, D) attn, values 0..4
    const float*         __restrict__ Wp,   // (D, D) f32
    const float*         __restrict__ bp,   // (D,)  f32
    float* __restrict__ out)                // (R, D) f32
{
    __shared__ unsigned short As [128 * 40];
    __shared__ unsigned short Wsh[ 64 * 40];
    __shared__ unsigned short Wsl[ 64 * 40];

    const int tid  = threadIdx.x;
    const int lane = tid & 63;
    const int wsub = tid >> 6;
    const int la   = lane & 15;
    const int lq   = lane >> 4;
    const int bd   = blockIdx.x;
    const int bm   = blockIdx.y;

    f32x4 acc[8];
    #pragma unroll
    for (int s = 0; s < 8; s++) acc[s] = (f32x4){0.f, 0.f, 0.f, 0.f};

    for (int kb = 0; kb < D_; kb += 32) {
        #pragma unroll
        for (int i = 0; i < 4; i++) {
            const int j   = tid + i * 256;
            const int row = j >> 3;
            const int kq  = (j & 7) * 4;
            uchar4 av = *reinterpret_cast<const uchar4*>(
                A + (size_t)(bm * 128 + row) * D_ + kb + kq);
            ushort4 h;
            h.x = (unsigned short)(__float_as_uint((float)av.x) >> 16);
            h.y = (unsigned short)(__float_as_uint((float)av.y) >> 16);
            h.z = (unsigned short)(__float_as_uint((float)av.z) >> 16);
            h.w = (unsigned short)(__float_as_uint((float)av.w) >> 16);
            *reinterpret_cast<ushort4*>(&As[row * 40 + kq]) = h;
        }
        #pragma unroll
        for (int i = 0; i < 2; i++) {
            const int j   = tid + i * 256;
            const int row = j >> 3;
            const int kq  = (j & 7) * 4;
            float4 wv = *reinterpret_cast<const float4*>(
                Wp + (size_t)(bd * 64 + row) * D_ + kb + kq);
            ushort4 h, l;
            split2bf16(wv.x, h.x, l.x);
            split2bf16(wv.y, h.y, l.y);
            split2bf16(wv.z, h.z, l.z);
            split2bf16(wv.w, h.w, l.w);
            *reinterpret_cast<ushort4*>(&Wsh[row * 40 + kq]) = h;
            *reinterpret_cast<ushort4*>(&Wsl[row * 40 + kq]) = l;
        }
        __syncthreads();

        const int brow = (wsub * 16 + la) * 40 + lq * 8;
        bf16x8 bh = *reinterpret_cast<const bf16x8*>(&Wsh[brow]);
        bf16x8 bl = *reinterpret_cast<const bf16x8*>(&Wsl[brow]);
        #pragma unroll
        for (int s = 0; s < 8; s++) {
            bf16x8 a = *reinterpret_cast<const bf16x8*>(&As[(s * 16 + la) * 40 + lq * 8]);
            acc[s] = __builtin_amdgcn_mfma_f32_16x16x32_bf16(a, bh, acc[s], 0, 0, 0);
            acc[s] = __builtin_amdgcn_mfma_f32_16x16x32_bf16(a, bl, acc[s], 0, 0, 0);
        }
        __syncthreads();
    }

    const int d    = bd * 64 + wsub * 16 + la;
    const float bias = bp[d];
    #pragma unroll
    for (int s = 0; s < 8; s++)
        #pragma unroll
        for (int i = 0; i < 4; i++) {
            const int m = bm * 128 + s * 16 + lq * 4 + i;
            out[(size_t)m * D_ + d] = acc[s][i] + bias;
        }
}

extern "C" void kernel_launch(void* const* d_in, const int* in_sizes, int n_in,
                              void* d_out, int out_size, void* d_ws, size_t ws_size,
                              hipStream_t stream) {
    const float* x  = (const float*)d_in[0];  // x_seq (T,B,N,D) f32
    const float* wq = (const float*)d_in[1];
    const float* wk = (const float*)d_in[2];
    const float* wv = (const float*)d_in[3];
    const float* wp = (const float*)d_in[4];
    const float* bp = (const float*)d_in[5];

    unsigned char* attn = (unsigned char*)d_ws;   // 33.5 MB, both paths
    dim3 blk(256);

    // Fast path workspace: attn [0,32M) | Wtiled [32M,+3M) | Xtiled [40M,+128M)
    const size_t OFF_WT  = 33554432;
    const size_t OFF_XT  = 41943040;
    const size_t NEED_FAST = OFF_XT + 134217728;  // 176,160,768 B

    if (ws_size >= NEED_FAST) {
        unsigned short* Wt = (unsigned short*)((char*)d_ws + OFF_WT);
        unsigned short* Xt = (unsigned short*)((char*)d_ws + OFF_XT);
        split_w_tiled<<<dim3(768),   blk, 0, stream>>>(wq, wk, wv, Wt);
        split_x_tiled<<<dim3(16384), blk, 0, stream>>>(x, Xt);
        dim3 g1(D_ / 64, M_ / 32);   // (8, 512); bd fastest -> X chunk L2 reuse
        proj_lif_attn_mfma_t<<<g1, blk, 0, stream>>>(x, wq, wk, wv, Xt, Wt, attn);
    } else {
        // Fallback: round-1 path (legacy layout: Wh/Wl after attn)
        unsigned short* Wh = (unsigned short*)((char*)d_ws + 33554432);
        unsigned short* Wl = (unsigned short*)((char*)d_ws + 33554432 + 1572864);
        split_w_kernel<<<dim3(768), blk, 0, stream>>>(wq, wk, wv, Wh, Wl);
        dim3 g1(D_ / 64, M_ / 32);
        proj_lif_attn_mfma<<<g1, blk, 0, stream>>>(x, wq, wk, wv, Wh, Wl, attn);
    }

    dim3 g2(D_ / 64, R_ / 128);  // (8, 512)
    attn_out_gemm_mfma<<<g2, blk, 0, stream>>>(attn, wp, bp, (float*)d_out);
}

// Round 3
// 812.471 us; speedup vs baseline: 1.7137x; 1.7137x over previous
//
#include <hip/hip_runtime.h>
#include <hip/hip_bf16.h>
#include <stdint.h>

// Problem constants (T, B, N, D) = (4, 16, 1024, 512); M = B*N
#define T_ 4
#define M_ 16384
#define D_ 512
#define R_ (T_ * M_)    // 65536 rows total
#define EPS_TRIG 1e-4f  // ~5 sigma of the bf16-split accumulation noise

typedef short bf16x8 __attribute__((ext_vector_type(8)));   // 8 bf16 (4 VGPRs)
typedef float f32x4  __attribute__((ext_vector_type(4)));
typedef unsigned short us8 __attribute__((ext_vector_type(8)));

// x = hi + lo + residual, |residual| <= 2^-17 |x|.
// hi: truncation (bit-chop); lo: RNE of the exact fp32 residual.
static __device__ __forceinline__ void split2bf16(float x, unsigned short& h, unsigned short& l) {
    unsigned int u = __float_as_uint(x);
    h = (unsigned short)(u >> 16);
    float r = x - __uint_as_float(u & 0xFFFF0000u);   // exact
    unsigned int v = __float_as_uint(r);
    l = (unsigned short)((v + 0x7FFFu + ((v >> 16) & 1u)) >> 16);
}

// Async global->LDS, 16 B per lane. LDS dest = wave-uniform base + lane*16.
static __device__ __forceinline__ void gload_lds16(const void* g, void* l) {
    __builtin_amdgcn_global_load_lds(
        (const __attribute__((address_space(1))) unsigned int*)g,
        (__attribute__((address_space(3))) unsigned int*)l,
        16, 0, 0);
}

// ---------------------------------------------------------------------------
// LEGACY kernel 0: one-shot W split -> Wh, Wl (row-major), fallback path only.
// ---------------------------------------------------------------------------
__global__ __launch_bounds__(256) void split_w_kernel(
    const float* __restrict__ Wq, const float* __restrict__ Wk, const float* __restrict__ Wv,
    unsigned short* __restrict__ Wh, unsigned short* __restrict__ Wl)
{
    const int idx4 = blockIdx.x * 256 + threadIdx.x;  // float4 index, < 196608
    const int flat = idx4 * 4;
    const int z    = flat >> 18;                      // 262144 elements per matrix
    const int off  = flat & 262143;
    const float* src = (z == 0) ? Wq : (z == 1) ? Wk : Wv;
    float4 v = *reinterpret_cast<const float4*>(src + off);
    ushort4 h, l;
    split2bf16(v.x, h.x, l.x);
    split2bf16(v.y, h.y, l.y);
    split2bf16(v.z, h.z, l.z);
    split2bf16(v.w, h.w, l.w);
    *reinterpret_cast<ushort4*>(Wh + flat) = h;
    *reinterpret_cast<ushort4*>(Wl + flat) = l;
}

// ---------------------------------------------------------------------------
// FAST kernel 0a: W split -> TILED layout for global_load_lds staging.
// Wtiled byte layout: [bd(8)][kbi(16)][wj(24)][dd(64)][16B], where
// wj = (hl*4+g)*3+z encodes (hl, k-granule g, z), dd = W row within d-slice.
// ---------------------------------------------------------------------------
__global__ __launch_bounds__(256) void split_w_tiled(
    const float* __restrict__ Wq, const float* __restrict__ Wk, const float* __restrict__ Wv,
    unsigned short* __restrict__ Wt)
{
    const int flat = blockIdx.x * 256 + threadIdx.x;  // 0..196607
    const int dd   = flat & 63;
    const int rest = flat >> 6;        // = bk*24 + wj
    const int wj   = rest % 24;
    const int bk   = rest / 24;        // bd*16 + kbi
    const int kbi  = bk & 15;
    const int bd   = bk >> 4;
    const int z    = wj % 3;
    const int hg   = wj / 3;
    const int hl   = hg >> 2;
    const int g    = hg & 3;

    const float* src = ((z == 0) ? Wq : (z == 1) ? Wk : Wv)
                       + (size_t)(bd * 64 + dd) * D_ + kbi * 32 + g * 8;
    float4 a = *reinterpret_cast<const float4*>(src);
    float4 b = *reinterpret_cast<const float4*>(src + 4);

    us8 hv, lv;
    unsigned short hh, ll;
    split2bf16(a.x, hh, ll); hv[0] = hh; lv[0] = ll;
    split2bf16(a.y, hh, ll); hv[1] = hh; lv[1] = ll;
    split2bf16(a.z, hh, ll); hv[2] = hh; lv[2] = ll;
    split2bf16(a.w, hh, ll); hv[3] = hh; lv[3] = ll;
    split2bf16(b.x, hh, ll); hv[4] = hh; lv[4] = ll;
    split2bf16(b.y, hh, ll); hv[5] = hh; lv[5] = ll;
    split2bf16(b.z, hh, ll); hv[6] = hh; lv[6] = ll;
    split2bf16(b.w, hh, ll); hv[7] = hh; lv[7] = ll;

    *reinterpret_cast<us8*>((char*)Wt + (size_t)flat * 16) = hl ? lv : hv;
}

// ---------------------------------------------------------------------------
// FAST kernel 0b: X split -> TILED layout.
// Xtiled byte layout: [bm(512)][kbi(16)][hl(2)][g(4)][row(128)][16B].
// ---------------------------------------------------------------------------
__global__ __launch_bounds__(256) void split_x_tiled(
    const float* __restrict__ X, unsigned short* __restrict__ Xt)
{
    const int flat = blockIdx.x * 256 + threadIdx.x;  // 0..4194303
    const int row  = flat & 127;
    const int g    = (flat >> 7) & 3;
    const int bk   = flat >> 9;        // bm*16 + kbi
    const int kbi  = bk & 15;
    const int bm   = bk >> 4;
    const int t    = row >> 5;
    const int mm   = row & 31;

    const float* src = X + (size_t)(t * M_ + bm * 32 + mm) * D_ + kbi * 32 + g * 8;
    float4 a = *reinterpret_cast<const float4*>(src);
    float4 b = *reinterpret_cast<const float4*>(src + 4);

    us8 hv, lv;
    unsigned short hh, ll;
    split2bf16(a.x, hh, ll); hv[0] = hh; lv[0] = ll;
    split2bf16(a.y, hh, ll); hv[1] = hh; lv[1] = ll;
    split2bf16(a.z, hh, ll); hv[2] = hh; lv[2] = ll;
    split2bf16(a.w, hh, ll); hv[3] = hh; lv[3] = ll;
    split2bf16(b.x, hh, ll); hv[4] = hh; lv[4] = ll;
    split2bf16(b.y, hh, ll); hv[5] = hh; lv[5] = ll;
    split2bf16(b.z, hh, ll); hv[6] = hh; lv[6] = ll;
    split2bf16(b.w, hh, ll); hv[7] = hh; lv[7] = ll;

    char* chunk = (char*)Xt + (size_t)bk * 16384;
    const int off = g * 2048 + row * 16;
    *reinterpret_cast<us8*>(chunk + off)        = hv;   // hl = 0 (hi)
    *reinterpret_cast<us8*>(chunk + 8192 + off) = lv;   // hl = 1 (lo)
}

// ---------------------------------------------------------------------------
// Shared epilogue: LIF (fp32) + WAVE-COOPERATIVE exact-f64 fixup + attn.
//
// Risky chains (|mem-1| < EPS_TRIG anywhere) occur ~1 per several waves.
// Old code: the owning lane alone walked a 512-step f64 loop with divergent
// scalar loads (~70k cyc, 63 lanes idle) -- this dominated the kernel.
// New code: ballot the risky lanes; for each, ALL 64 lanes cooperatively
// compute the f64 dot (lane j covers k=8j..8j+7, coalesced float4 loads,
// f64 butterfly reduce), then the f64 LIF chain is redone by everyone and
// the owner keeps the corrected spikes. ~1-2k cyc per event.
// ---------------------------------------------------------------------------
static __device__ __forceinline__ void lif_attn_epilogue(
    f32x4 (&acc)[2][3][T_], const float* __restrict__ X,
    const float* __restrict__ Wq, const float* __restrict__ Wk, const float* __restrict__ Wv,
    unsigned char* __restrict__ attn, int bd, int bm, int wsub, int la, int lq, int lane)
{
    const int d = bd * 64 + wsub * 16 + la;
    #pragma unroll
    for (int s = 0; s < 2; s++)
        #pragma unroll
        for (int i = 0; i < 4; i++) {
            const int m = bm * 32 + s * 16 + lq * 4 + i;
            int sp[3][T_];
            int zrisky = 0;
            #pragma unroll
            for (int z = 0; z < 3; z++) {
                float mem = 0.f;
                #pragma unroll
                for (int t = 0; t < T_; t++) {
                    mem = 0.9f * mem + acc[s][z][t][i];
                    if (fabsf(mem - 1.0f) < EPS_TRIG) zrisky |= (1 << z);
                    const int sb = (mem >= 1.0f) ? 1 : 0;
                    sp[z][t] = sb;
                    mem -= (float)sb;
                }
            }
            // Wave-cooperative fixup. ball is wave-uniform -> no divergence
            // on the loop structure; shfl/ballot are full-wave operations.
            unsigned long long ball = __ballot(zrisky != 0);
            while (ball) {
                const int src = (int)__builtin_ctzll(ball);
                ball &= ball - 1;
                const int bits = __shfl(zrisky, src);
                const int m_s  = bm * 32 + s * 16 + (src >> 4) * 4 + i;
                const int d_s  = bd * 64 + wsub * 16 + (src & 15);
                #pragma unroll
                for (int z = 0; z < 3; z++) {
                    if (!(bits & (1 << z))) continue;
                    const float* Wrow = ((z == 0) ? Wq : (z == 1) ? Wk : Wv) + (size_t)d_s * D_;
                    float4 w0 = *reinterpret_cast<const float4*>(Wrow + lane * 8);
                    float4 w1 = *reinterpret_cast<const float4*>(Wrow + lane * 8 + 4);
                    double pre[T_];
                    #pragma unroll
                    for (int t = 0; t < T_; t++) {
                        const float* xrow = X + (size_t)(t * M_ + m_s) * D_ + lane * 8;
                        float4 x0 = *reinterpret_cast<const float4*>(xrow);
                        float4 x1 = *reinterpret_cast<const float4*>(xrow + 4);
                        double p = (double)x0.x * (double)w0.x + (double)x0.y * (double)w0.y
                                 + (double)x0.z * (double)w0.z + (double)x0.w * (double)w0.w
                                 + (double)x1.x * (double)w1.x + (double)x1.y * (double)w1.y
                                 + (double)x1.z * (double)w1.z + (double)x1.w * (double)w1.w;
                        #pragma unroll
                        for (int off = 32; off > 0; off >>= 1)
                            p += __shfl_xor(p, off, 64);
                        pre[t] = p;   // full dot, identical in all lanes
                    }
                    double dm = 0.0;
                    int spz[T_];
                    #pragma unroll
                    for (int t = 0; t < T_; t++) {
                        dm = 0.9 * dm + pre[t];
                        const int sb = (dm >= 1.0) ? 1 : 0;
                        spz[t] = sb;
                        dm -= (double)sb;
                    }
                    if (lane == src) {
                        #pragma unroll
                        for (int t = 0; t < T_; t++) sp[z][t] = spz[t];
                    }
                }
            }
            int ctx = 0;
            #pragma unroll
            for (int t = 0; t < T_; t++) {
                ctx += sp[1][t] & sp[2][t];
                attn[(size_t)(t * M_ + m) * D_ + d] = (unsigned char)(sp[0][t] ? ctx : 0);
            }
        }
}

// ---------------------------------------------------------------------------
// FAST kernel 1: projection via bf16 MFMA, global_load_lds staging,
// DOUBLE-BUFFERED (T3 minimal 2-phase): issue next tile's loads before the
// MFMA phase; single barrier per iter drains them while MFMAs covered the
// latency. LDS 80 KB (2 buffers) -> 2 blocks/CU (VGPR-limited anyway).
// MFMA operand values bit-identical to the legacy kernel.
// ---------------------------------------------------------------------------
__global__ __launch_bounds__(256) void proj_lif_attn_mfma_t(
    const float* __restrict__ X,
    const float* __restrict__ Wq, const float* __restrict__ Wk, const float* __restrict__ Wv,
    const unsigned short* __restrict__ XtS, const unsigned short* __restrict__ WtS,
    unsigned char* __restrict__ attn)
{
    __shared__ unsigned short Xs[2][8192];    // [buf][hl(2)][g(4)][row(128)][8] 32 KB
    __shared__ unsigned short Ws[2][12288];   // [buf][hl(2)][g(4)][zdd(192)][8] 48 KB

    const int tid  = threadIdx.x;
    const int lane = tid & 63;
    const int wsub = tid >> 6;     // 0..3 -> 16-d subtile
    const int la   = lane & 15;
    const int lq   = lane >> 4;
    const int bd   = blockIdx.x;   // 0..7   (64 d per block)
    const int bm   = blockIdx.y;   // 0..511 (32 m per block)

    f32x4 acc[2][3][T_];
    #pragma unroll
    for (int s = 0; s < 2; s++)
        #pragma unroll
        for (int z = 0; z < 3; z++)
            #pragma unroll
            for (int t = 0; t < T_; t++)
                acc[s][z][t] = (f32x4){0.f, 0.f, 0.f, 0.f};

    // Per-wave staging: X slabs (4 x 1024 B), W slabs (6 x 1024 B). Source
    // chunk interior is byte-identical to one LDS buffer, so
    // src = chunk + slab*1024 + lane*16.
    const char* xsrc0 = (const char*)XtS + ((size_t)(bm * 16)) * 16384 + (wsub * 4) * 1024 + lane * 16;
    const char* wsrc0 = (const char*)WtS + ((size_t)(bd * 16)) * 24576 + (wsub * 6) * 1024 + lane * 16;

    // prologue: stage kbi=0 into buf 0
    {
        char* xdst = (char*)&Xs[0][0] + (wsub * 4) * 1024;
        char* wdst = (char*)&Ws[0][0] + (wsub * 6) * 1024;
        #pragma unroll
        for (int i = 0; i < 4; i++) gload_lds16(xsrc0 + i * 1024, xdst + i * 1024);
        #pragma unroll
        for (int j = 0; j < 6; j++) gload_lds16(wsrc0 + j * 1024, wdst + j * 1024);
    }
    __syncthreads();   // compiler drains vmcnt(0) before the barrier

    for (int kbi = 0; kbi < 16; kbi++) {
        const int cur = kbi & 1;
        // issue next tile's async loads into the other buffer
        if (kbi < 15) {
            const char* xs = xsrc0 + (size_t)(kbi + 1) * 16384;
            const char* ws = wsrc0 + (size_t)(kbi + 1) * 24576;
            char* xdst = (char*)&Xs[cur ^ 1][0] + (wsub * 4) * 1024;
            char* wdst = (char*)&Ws[cur ^ 1][0] + (wsub * 6) * 1024;
            #pragma unroll
            for (int i = 0; i < 4; i++) gload_lds16(xs + i * 1024, xdst + i * 1024);
            #pragma unroll
            for (int j = 0; j < 6; j++) gload_lds16(ws + j * 1024, wdst + j * 1024);
        }

        const unsigned short* Xc = &Xs[cur][0];
        const unsigned short* Wc = &Ws[cur][0];
        bf16x8 bh[3], bl[3];
        #pragma unroll
        for (int z = 0; z < 3; z++) {
            const int wbase = lq * 1536 + z * 512 + wsub * 128 + la * 8;
            bh[z] = *reinterpret_cast<const bf16x8*>(&Wc[wbase]);
            bl[z] = *reinterpret_cast<const bf16x8*>(&Wc[6144 + wbase]);
        }
        #pragma unroll
        for (int s = 0; s < 2; s++)
            #pragma unroll
            for (int t = 0; t < T_; t++) {
                const int abase = lq * 1024 + (t * 32 + s * 16 + la) * 8;
                bf16x8 ah = *reinterpret_cast<const bf16x8*>(&Xc[abase]);
                bf16x8 al = *reinterpret_cast<const bf16x8*>(&Xc[4096 + abase]);
                #pragma unroll
                for (int z = 0; z < 3; z++) {
                    acc[s][z][t] = __builtin_amdgcn_mfma_f32_16x16x32_bf16(ah, bh[z], acc[s][z][t], 0, 0, 0);
                    acc[s][z][t] = __builtin_amdgcn_mfma_f32_16x16x32_bf16(ah, bl[z], acc[s][z][t], 0, 0, 0);
                    acc[s][z][t] = __builtin_amdgcn_mfma_f32_16x16x32_bf16(al, bh[z], acc[s][z][t], 0, 0, 0);
                }
            }
        __syncthreads();   // drains this iter's async loads; next buf ready
    }

    lif_attn_epilogue(acc, X, Wq, Wk, Wv, attn, bd, bm, wsub, la, lq, lane);
}

// ---------------------------------------------------------------------------
// LEGACY kernel 1 (fallback when workspace too small).
// ---------------------------------------------------------------------------
__global__ __launch_bounds__(256) void proj_lif_attn_mfma(
    const float* __restrict__ X,
    const float* __restrict__ Wq, const float* __restrict__ Wk, const float* __restrict__ Wv,
    const unsigned short* __restrict__ WhS, const unsigned short* __restrict__ WlS,
    unsigned char* __restrict__ attn)
{
    __shared__ unsigned short XsH[128 * 40];
    __shared__ unsigned short XsL[128 * 40];
    __shared__ unsigned short WsH[192 * 40];
    __shared__ unsigned short WsL[192 * 40];

    const int tid  = threadIdx.x;
    const int lane = tid & 63;
    const int wsub = tid >> 6;
    const int la   = lane & 15;
    const int lq   = lane >> 4;
    const int bd   = blockIdx.x;
    const int bm   = blockIdx.y;

    f32x4 acc[2][3][T_];
    #pragma unroll
    for (int s = 0; s < 2; s++)
        #pragma unroll
        for (int z = 0; z < 3; z++)
            #pragma unroll
            for (int t = 0; t < T_; t++)
                acc[s][z][t] = (f32x4){0.f, 0.f, 0.f, 0.f};

    for (int kb = 0; kb < D_; kb += 32) {
        #pragma unroll
        for (int i = 0; i < 4; i++) {
            const int j   = tid + i * 256;
            const int row = j >> 3;
            const int kq  = (j & 7) * 4;
            const int t   = row >> 5;
            const int mm  = row & 31;
            float4 xv = *reinterpret_cast<const float4*>(
                X + ((size_t)(t * M_ + bm * 32 + mm) * D_ + kb + kq));
            ushort4 h, l;
            split2bf16(xv.x, h.x, l.x);
            split2bf16(xv.y, h.y, l.y);
            split2bf16(xv.z, h.z, l.z);
            split2bf16(xv.w, h.w, l.w);
            *reinterpret_cast<ushort4*>(&XsH[row * 40 + kq]) = h;
            *reinterpret_cast<ushort4*>(&XsL[row * 40 + kq]) = l;
        }
        {
            const int wd  = tid >> 2;
            const int wkg = tid & 3;
            #pragma unroll
            for (int z = 0; z < 3; z++) {
                const size_t goff = (size_t)(z * D_ + bd * 64 + wd) * D_ + kb + wkg * 8;
                int4 hv = *reinterpret_cast<const int4*>(WhS + goff);
                int4 lv = *reinterpret_cast<const int4*>(WlS + goff);
                *reinterpret_cast<int4*>(&WsH[(z * 64 + wd) * 40 + wkg * 8]) = hv;
                *reinterpret_cast<int4*>(&WsL[(z * 64 + wd) * 40 + wkg * 8]) = lv;
            }
        }
        __syncthreads();

        bf16x8 bh[3], bl[3];
        #pragma unroll
        for (int z = 0; z < 3; z++) {
            const int brow = (z * 64 + wsub * 16 + la) * 40 + lq * 8;
            bh[z] = *reinterpret_cast<const bf16x8*>(&WsH[brow]);
            bl[z] = *reinterpret_cast<const bf16x8*>(&WsL[brow]);
        }
        #pragma unroll
        for (int s = 0; s < 2; s++)
            #pragma unroll
            for (int t = 0; t < T_; t++) {
                const int arow = (t * 32 + s * 16 + la) * 40 + lq * 8;
                bf16x8 ah = *reinterpret_cast<const bf16x8*>(&XsH[arow]);
                bf16x8 al = *reinterpret_cast<const bf16x8*>(&XsL[arow]);
                #pragma unroll
                for (int z = 0; z < 3; z++) {
                    acc[s][z][t] = __builtin_amdgcn_mfma_f32_16x16x32_bf16(ah, bh[z], acc[s][z][t], 0, 0, 0);
                    acc[s][z][t] = __builtin_amdgcn_mfma_f32_16x16x32_bf16(ah, bl[z], acc[s][z][t], 0, 0, 0);
                    acc[s][z][t] = __builtin_amdgcn_mfma_f32_16x16x32_bf16(al, bh[z], acc[s][z][t], 0, 0, 0);
                }
            }
        __syncthreads();
    }

    lif_attn_epilogue(acc, X, Wq, Wk, Wv, attn, bd, bm, wsub, la, lq, lane);
}

// ---------------------------------------------------------------------------
// Kernel 2: out = attn @ Wp^T + bp via bf16 MFMA (unchanged, known good).
// ---------------------------------------------------------------------------
__global__ __launch_bounds__(256) void attn_out_gemm_mfma(
    const unsigned char* __restrict__ A,    // (R, D) attn, values 0..4
    const float*         __restrict__ Wp,   // (D, D) f32
    const float*         __restrict__ bp,   // (D,)  f32
    float* __restrict__ out)                // (R, D) f32
{
    __shared__ unsigned short As [128 * 40];
    __shared__ unsigned short Wsh[ 64 * 40];
    __shared__ unsigned short Wsl[ 64 * 40];

    const int tid  = threadIdx.x;
    const int lane = tid & 63;
    const int wsub = tid >> 6;
    const int la   = lane & 15;
    const int lq   = lane >> 4;
    const int bd   = blockIdx.x;
    const int bm   = blockIdx.y;

    f32x4 acc[8];
    #pragma unroll
    for (int s = 0; s < 8; s++) acc[s] = (f32x4){0.f, 0.f, 0.f, 0.f};

    for (int kb = 0; kb < D_; kb += 32) {
        #pragma unroll
        for (int i = 0; i < 4; i++) {
            const int j   = tid + i * 256;
            const int row = j >> 3;
            const int kq  = (j & 7) * 4;
            uchar4 av = *reinterpret_cast<const uchar4*>(
                A + (size_t)(bm * 128 + row) * D_ + kb + kq);
            ushort4 h;
            h.x = (unsigned short)(__float_as_uint((float)av.x) >> 16);
            h.y = (unsigned short)(__float_as_uint((float)av.y) >> 16);
            h.z = (unsigned short)(__float_as_uint((float)av.z) >> 16);
            h.w = (unsigned short)(__float_as_uint((float)av.w) >> 16);
            *reinterpret_cast<ushort4*>(&As[row * 40 + kq]) = h;
        }
        #pragma unroll
        for (int i = 0; i < 2; i++) {
            const int j   = tid + i * 256;
            const int row = j >> 3;
            const int kq  = (j & 7) * 4;
            float4 wv = *reinterpret_cast<const float4*>(
                Wp + (size_t)(bd * 64 + row) * D_ + kb + kq);
            ushort4 h, l;
            split2bf16(wv.x, h.x, l.x);
            split2bf16(wv.y, h.y, l.y);
            split2bf16(wv.z, h.z, l.z);
            split2bf16(wv.w, h.w, l.w);
            *reinterpret_cast<ushort4*>(&Wsh[row * 40 + kq]) = h;
            *reinterpret_cast<ushort4*>(&Wsl[row * 40 + kq]) = l;
        }
        __syncthreads();

        const int brow = (wsub * 16 + la) * 40 + lq * 8;
        bf16x8 bh = *reinterpret_cast<const bf16x8*>(&Wsh[brow]);
        bf16x8 bl = *reinterpret_cast<const bf16x8*>(&Wsl[brow]);
        #pragma unroll
        for (int s = 0; s < 8; s++) {
            bf16x8 a = *reinterpret_cast<const bf16x8*>(&As[(s * 16 + la) * 40 + lq * 8]);
            acc[s] = __builtin_amdgcn_mfma_f32_16x16x32_bf16(a, bh, acc[s], 0, 0, 0);
            acc[s] = __builtin_amdgcn_mfma_f32_16x16x32_bf16(a, bl, acc[s], 0, 0, 0);
        }
        __syncthreads();
    }

    const int d    = bd * 64 + wsub * 16 + la;
    const float bias = bp[d];
    #pragma unroll
    for (int s = 0; s < 8; s++)
        #pragma unroll
        for (int i = 0; i < 4; i++) {
            const int m = bm * 128 + s * 16 + lq * 4 + i;
            out[(size_t)m * D_ + d] = acc[s][i] + bias;
        }
}

extern "C" void kernel_launch(void* const* d_in, const int* in_sizes, int n_in,
                              void* d_out, int out_size, void* d_ws, size_t ws_size,
                              hipStream_t stream) {
    const float* x  = (const float*)d_in[0];  // x_seq (T,B,N,D) f32
    const float* wq = (const float*)d_in[1];
    const float* wk = (const float*)d_in[2];
    const float* wv = (const float*)d_in[3];
    const float* wp = (const float*)d_in[4];
    const float* bp = (const float*)d_in[5];

    unsigned char* attn = (unsigned char*)d_ws;   // 33.5 MB, both paths
    dim3 blk(256);

    // Fast path workspace: attn [0,32M) | Wtiled [32M,+3M) | Xtiled [40M,+128M)
    const size_t OFF_WT  = 33554432;
    const size_t OFF_XT  = 41943040;
    const size_t NEED_FAST = OFF_XT + 134217728;  // 176,160,768 B

    if (ws_size >= NEED_FAST) {
        unsigned short* Wt = (unsigned short*)((char*)d_ws + OFF_WT);
        unsigned short* Xt = (unsigned short*)((char*)d_ws + OFF_XT);
        split_w_tiled<<<dim3(768),   blk, 0, stream>>>(wq, wk, wv, Wt);
        split_x_tiled<<<dim3(16384), blk, 0, stream>>>(x, Xt);
        dim3 g1(D_ / 64, M_ / 32);   // (8, 512); bd fastest -> X chunk L2 reuse
        proj_lif_attn_mfma_t<<<g1, blk, 0, stream>>>(x, wq, wk, wv, Xt, Wt, attn);
    } else {
        // Fallback: round-1 path (legacy layout: Wh/Wl after attn)
        unsigned short* Wh = (unsigned short*)((char*)d_ws + 33554432);
        unsigned short* Wl = (unsigned short*)((char*)d_ws + 33554432 + 1572864);
        split_w_kernel<<<dim3(768), blk, 0, stream>>>(wq, wk, wv, Wh, Wl);
        dim3 g1(D_ / 64, M_ / 32);
        proj_lif_attn_mfma<<<g1, blk, 0, stream>>>(x, wq, wk, wv, Wh, Wl, attn);
    }

    dim3 g2(D_ / 64, R_ / 128);  // (8, 512)
    attn_out_gemm_mfma<<<g2, blk, 0, stream>>>(attn, wp, bp, (float*)d_out);
}

// Round 4
// 559.834 us; speedup vs baseline: 2.4871x; 1.4513x over previous
//
#include <hip/hip_runtime.h>
#include <hip/hip_bf16.h>
#include <stdint.h>

// Problem constants (T, B, N, D) = (4, 16, 1024, 512); M = B*N
#define T_ 4
#define M_ 16384
#define D_ 512
#define R_ (T_ * M_)    // 65536 rows total
#define EPS_TRIG 1e-4f  // ~5 sigma of the bf16-split accumulation noise

typedef short bf16x8 __attribute__((ext_vector_type(8)));   // 8 bf16 (4 VGPRs)
typedef float f32x4  __attribute__((ext_vector_type(4)));
typedef unsigned short us8 __attribute__((ext_vector_type(8)));

// x = hi + lo + residual, |residual| <= 2^-17 |x|.
static __device__ __forceinline__ void split2bf16(float x, unsigned short& h, unsigned short& l) {
    unsigned int u = __float_as_uint(x);
    h = (unsigned short)(u >> 16);
    float r = x - __uint_as_float(u & 0xFFFF0000u);   // exact
    unsigned int v = __float_as_uint(r);
    l = (unsigned short)((v + 0x7FFFu + ((v >> 16) & 1u)) >> 16);
}

// Async global->LDS, 16 B per lane. LDS dest = wave-uniform base + lane*16;
// the GLOBAL source address is per-lane.
static __device__ __forceinline__ void gload_lds16(const void* g, void* l) {
    __builtin_amdgcn_global_load_lds(
        (const __attribute__((address_space(1))) unsigned int*)g,
        (__attribute__((address_space(3))) unsigned int*)l,
        16, 0, 0);
}

// ---------------------------------------------------------------------------
// Kernel 0a: Wq/Wk/Wv split -> TILED layout (UNCHANGED layout from round 2/3).
// Wtiled: [bd(8)][kbi(16)][wj(24)][dd(64)][16B], wj=(hl*4+g)*3+z.
// Per-(bd,kbi) chunk = 24576 B. Fragment offset inside chunk:
//   hl*12288 + g*3072 + z*1024 + dd*16   (g = k-granule = lq, dd = wsub*16+la)
// ---------------------------------------------------------------------------
__global__ __launch_bounds__(256) void split_w_tiled(
    const float* __restrict__ Wq, const float* __restrict__ Wk, const float* __restrict__ Wv,
    unsigned short* __restrict__ Wt)
{
    const int flat = blockIdx.x * 256 + threadIdx.x;  // 0..196607
    const int dd   = flat & 63;
    const int rest = flat >> 6;        // = bk*24 + wj
    const int wj   = rest % 24;
    const int bk   = rest / 24;        // bd*16 + kbi
    const int kbi  = bk & 15;
    const int bd   = bk >> 4;
    const int z    = wj % 3;
    const int hg   = wj / 3;
    const int hl   = hg >> 2;
    const int g    = hg & 3;

    const float* src = ((z == 0) ? Wq : (z == 1) ? Wk : Wv)
                       + (size_t)(bd * 64 + dd) * D_ + kbi * 32 + g * 8;
    float4 a = *reinterpret_cast<const float4*>(src);
    float4 b = *reinterpret_cast<const float4*>(src + 4);

    us8 hv, lv;
    unsigned short hh, ll;
    split2bf16(a.x, hh, ll); hv[0] = hh; lv[0] = ll;
    split2bf16(a.y, hh, ll); hv[1] = hh; lv[1] = ll;
    split2bf16(a.z, hh, ll); hv[2] = hh; lv[2] = ll;
    split2bf16(a.w, hh, ll); hv[3] = hh; lv[3] = ll;
    split2bf16(b.x, hh, ll); hv[4] = hh; lv[4] = ll;
    split2bf16(b.y, hh, ll); hv[5] = hh; lv[5] = ll;
    split2bf16(b.z, hh, ll); hv[6] = hh; lv[6] = ll;
    split2bf16(b.w, hh, ll); hv[7] = hh; lv[7] = ll;

    *reinterpret_cast<us8*>((char*)Wt + (size_t)flat * 16) = hl ? lv : hv;
}

// ---------------------------------------------------------------------------
// Kernel 0b: Wp split -> TILED layout for the output GEMM.
// WpT: per-(bd,kbi) chunk = 8192 B, layout [hl(2)][g(4)][dd(64)][16B].
// Fragment offset: hl*4096 + g*1024 + dd*16.
// ---------------------------------------------------------------------------
__global__ __launch_bounds__(256) void split_wp_tiled(
    const float* __restrict__ Wp, unsigned short* __restrict__ WpT)
{
    const int flat = blockIdx.x * 256 + threadIdx.x;  // 0..32767
    const int dd   = flat & 63;
    const int g    = (flat >> 6) & 3;
    const int kbi  = (flat >> 8) & 15;
    const int bd   = flat >> 12;

    const float* src = Wp + (size_t)(bd * 64 + dd) * D_ + kbi * 32 + g * 8;
    float4 a = *reinterpret_cast<const float4*>(src);
    float4 b = *reinterpret_cast<const float4*>(src + 4);

    us8 hv, lv;
    unsigned short hh, ll;
    split2bf16(a.x, hh, ll); hv[0] = hh; lv[0] = ll;
    split2bf16(a.y, hh, ll); hv[1] = hh; lv[1] = ll;
    split2bf16(a.z, hh, ll); hv[2] = hh; lv[2] = ll;
    split2bf16(a.w, hh, ll); hv[3] = hh; lv[3] = ll;
    split2bf16(b.x, hh, ll); hv[4] = hh; lv[4] = ll;
    split2bf16(b.y, hh, ll); hv[5] = hh; lv[5] = ll;
    split2bf16(b.z, hh, ll); hv[6] = hh; lv[6] = ll;
    split2bf16(b.w, hh, ll); hv[7] = hh; lv[7] = ll;

    char* chunk = (char*)WpT + (size_t)(bd * 16 + kbi) * 8192;
    *reinterpret_cast<us8*>(chunk + g * 1024 + dd * 16)        = hv;
    *reinterpret_cast<us8*>(chunk + 4096 + g * 1024 + dd * 16) = lv;
}

// ---------------------------------------------------------------------------
// Kernel 0c: X split -> TILED layout v3 (16-m chunks, coalesced both ways).
// Xt: per-(bmp,kbi) chunk = 8192 B, layout [hl(2)][g(4)][row'(64)][16B],
// row' = t*16 + mm, bmp = 16-row group (1024 of them).
// Reads: 4 consecutive lanes cover 128 contiguous B of one X row.
// Writes: per wave 8 segments of 256 contiguous B.
// ---------------------------------------------------------------------------
__global__ __launch_bounds__(256) void split_x_tiled3(
    const float* __restrict__ X, unsigned short* __restrict__ Xt)
{
    const int bmp  = blockIdx.x;       // 0..1023
    const int tid  = threadIdx.x;
    const int rowp = tid >> 2;         // 0..63 = t*16+mm
    const int g    = tid & 3;
    const int t    = rowp >> 4;
    const int mm   = rowp & 15;

    const float* srow = X + (size_t)(t * M_ + bmp * 16 + mm) * D_;

    for (int kb = 0; kb < 16; kb++) {
        const float* src = srow + kb * 32 + g * 8;
        float4 a = *reinterpret_cast<const float4*>(src);
        float4 b = *reinterpret_cast<const float4*>(src + 4);

        us8 hv, lv;
        unsigned short hh, ll;
        split2bf16(a.x, hh, ll); hv[0] = hh; lv[0] = ll;
        split2bf16(a.y, hh, ll); hv[1] = hh; lv[1] = ll;
        split2bf16(a.z, hh, ll); hv[2] = hh; lv[2] = ll;
        split2bf16(a.w, hh, ll); hv[3] = hh; lv[3] = ll;
        split2bf16(b.x, hh, ll); hv[4] = hh; lv[4] = ll;
        split2bf16(b.y, hh, ll); hv[5] = hh; lv[5] = ll;
        split2bf16(b.z, hh, ll); hv[6] = hh; lv[6] = ll;
        split2bf16(b.w, hh, ll); hv[7] = hh; lv[7] = ll;

        char* chunk = (char*)Xt + (size_t)(bmp * 16 + kb) * 8192;
        *reinterpret_cast<us8*>(chunk + g * 1024 + rowp * 16)        = hv;
        *reinterpret_cast<us8*>(chunk + 4096 + g * 1024 + rowp * 16) = lv;
    }
}

// ---------------------------------------------------------------------------
// Kernel 1: projection + LIF + fixup + attn.  v4.
//
// Changes vs round 3 (theory: occupancy-starved at 1 block/CU):
//  - W fragments: NO LDS (zero reuse across waves/iters) -> direct global
//    bf16x8 loads from Wt (L2-hot, 384 KB per bd).  LDS = X only, 16 KB.
//  - m-tile 32 -> 16 (acc 96 -> 48 VGPR), __launch_bounds__(256,4)
//    targets <=128 VGPR -> 4 blocks/CU (16 waves) instead of 1 block.
//  - XCD co-location remap: the 8 bd-siblings of each bmp run consecutively
//    on ONE XCD -> X chunk read ~once from HBM instead of ~8x.
// MFMA operand values remain bit-identical to rounds 0-3.
// ---------------------------------------------------------------------------
__global__ __launch_bounds__(256, 4) void proj_lif_attn_v4(
    const float* __restrict__ X,
    const float* __restrict__ Wq, const float* __restrict__ Wk, const float* __restrict__ Wv,
    const unsigned short* __restrict__ XtS, const unsigned short* __restrict__ WtS,
    unsigned char* __restrict__ attn)
{
    __shared__ unsigned short Xs[2][4096];   // 2 x 8 KB: [hl(2)][g(4)][row'(64)][16B]

    const int tid  = threadIdx.x;
    const int lane = tid & 63;
    const int wsub = tid >> 6;     // 0..3 -> 16-d subtile
    const int la   = lane & 15;
    const int lq   = lane >> 4;

    // bijective XCD co-location remap (8 XCDs, x-fastest dispatch):
    // XCD x gets n === x (mod 8): bd cycles 0..7 while bmp stays fixed for
    // 8 consecutive same-XCD blocks; each XCD owns bmp range [x*128,(x+1)*128).
    const int n   = blockIdx.y * 8 + blockIdx.x;   // 0..8191
    const int bd  = (n >> 3) & 7;
    const int bmp = (n & 7) * 128 + (n >> 6);      // 0..1023 (16-m group)

    f32x4 acc[3][T_];
    #pragma unroll
    for (int z = 0; z < 3; z++)
        #pragma unroll
        for (int t = 0; t < T_; t++)
            acc[z][t] = (f32x4){0.f, 0.f, 0.f, 0.f};

    const char* xsrc0 = (const char*)XtS + (size_t)(bmp * 16) * 8192 + wsub * 2048 + lane * 16;
    const char* wb    = (const char*)WtS + (size_t)(bd * 16) * 24576 + lq * 3072 + wsub * 256 + la * 16;
    char* xd0 = (char*)&Xs[0][0] + wsub * 2048;
    char* xd1 = (char*)&Xs[1][0] + wsub * 2048;

    // prologue: stage kbi=0 into buf 0 (wave wsub stages bytes [wsub*2048,+2048))
    gload_lds16(xsrc0,        xd0);
    gload_lds16(xsrc0 + 1024, xd0 + 1024);
    __syncthreads();

    for (int kbi = 0; kbi < 16; kbi++) {
        const int cur = kbi & 1;

        // W fragments straight from global (issued first so their waitcnt
        // does not imply the X prefetch drained)
        bf16x8 bh[3], bl[3];
        #pragma unroll
        for (int z = 0; z < 3; z++) {
            const char* p = wb + (size_t)kbi * 24576 + z * 1024;
            bh[z] = *reinterpret_cast<const bf16x8*>(p);
            bl[z] = *reinterpret_cast<const bf16x8*>(p + 12288);
        }

        // prefetch next X tile into the other buffer
        if (kbi < 15) {
            const char* xs = xsrc0 + (size_t)(kbi + 1) * 8192;
            char* xd = cur ? xd0 : xd1;
            gload_lds16(xs,        xd);
            gload_lds16(xs + 1024, xd + 1024);
        }

        const char* Xc = (const char*)&Xs[cur][0];
        #pragma unroll
        for (int t = 0; t < T_; t++) {
            const int ab = lq * 1024 + (t * 16 + la) * 16;   // conflict-free
            bf16x8 ah = *reinterpret_cast<const bf16x8*>(Xc + ab);
            bf16x8 al = *reinterpret_cast<const bf16x8*>(Xc + 4096 + ab);
            #pragma unroll
            for (int z = 0; z < 3; z++) {
                acc[z][t] = __builtin_amdgcn_mfma_f32_16x16x32_bf16(ah, bh[z], acc[z][t], 0, 0, 0);
                acc[z][t] = __builtin_amdgcn_mfma_f32_16x16x32_bf16(ah, bl[z], acc[z][t], 0, 0, 0);
                acc[z][t] = __builtin_amdgcn_mfma_f32_16x16x32_bf16(al, bh[z], acc[z][t], 0, 0, 0);
            }
        }
        __syncthreads();   // drains this iter's prefetch; next buf ready
    }

    // Epilogue: LIF (fp32) + wave-cooperative exact-f64 fixup + attn
    const int d = bd * 64 + wsub * 16 + la;
    #pragma unroll
    for (int i = 0; i < 4; i++) {
        const int m = bmp * 16 + lq * 4 + i;
        int sp[3][T_];
        int zrisky = 0;
        #pragma unroll
        for (int z = 0; z < 3; z++) {
            float mem = 0.f;
            #pragma unroll
            for (int t = 0; t < T_; t++) {
                mem = 0.9f * mem + acc[z][t][i];
                if (fabsf(mem - 1.0f) < EPS_TRIG) zrisky |= (1 << z);
                const int sb = (mem >= 1.0f) ? 1 : 0;
                sp[z][t] = sb;
                mem -= (float)sb;
            }
        }
        unsigned long long ball = __ballot(zrisky != 0);
        while (ball) {
            const int src = (int)__builtin_ctzll(ball);
            ball &= ball - 1;
            const int bits = __shfl(zrisky, src);
            const int m_s  = bmp * 16 + (src >> 4) * 4 + i;
            const int d_s  = bd * 64 + wsub * 16 + (src & 15);
            #pragma unroll
            for (int z = 0; z < 3; z++) {
                if (!(bits & (1 << z))) continue;
                const float* Wrow = ((z == 0) ? Wq : (z == 1) ? Wk : Wv) + (size_t)d_s * D_;
                float4 w0 = *reinterpret_cast<const float4*>(Wrow + lane * 8);
                float4 w1 = *reinterpret_cast<const float4*>(Wrow + lane * 8 + 4);
                double pre[T_];
                #pragma unroll
                for (int t = 0; t < T_; t++) {
                    const float* xrow = X + (size_t)(t * M_ + m_s) * D_ + lane * 8;
                    float4 x0 = *reinterpret_cast<const float4*>(xrow);
                    float4 x1 = *reinterpret_cast<const float4*>(xrow + 4);
                    double p = (double)x0.x * (double)w0.x + (double)x0.y * (double)w0.y
                             + (double)x0.z * (double)w0.z + (double)x0.w * (double)w0.w
                             + (double)x1.x * (double)w1.x + (double)x1.y * (double)w1.y
                             + (double)x1.z * (double)w1.z + (double)x1.w * (double)w1.w;
                    #pragma unroll
                    for (int off = 32; off > 0; off >>= 1)
                        p += __shfl_xor(p, off, 64);
                    pre[t] = p;
                }
                double dm = 0.0;
                int spz[T_];
                #pragma unroll
                for (int t = 0; t < T_; t++) {
                    dm = 0.9 * dm + pre[t];
                    const int sb = (dm >= 1.0) ? 1 : 0;
                    spz[t] = sb;
                    dm -= (double)sb;
                }
                if (lane == src) {
                    #pragma unroll
                    for (int t = 0; t < T_; t++) sp[z][t] = spz[t];
                }
            }
        }
        int ctx = 0;
        #pragma unroll
        for (int t = 0; t < T_; t++) {
            ctx += sp[1][t] & sp[2][t];
            attn[(size_t)(t * M_ + m) * D_ + d] = (unsigned char)(sp[0][t] ? ctx : 0);
        }
    }
}

// ---------------------------------------------------------------------------
// Kernel 2: out = attn @ Wp^T + bp via bf16 MFMA.  v2.
//  - W fragments from pre-split tiled WpT via direct global loads (no W LDS,
//    no per-iter split VALU); LDS = A tile only (10 KB).
//  - A prefetched into registers one K-step ahead (hides HBM latency under
//    the compute phase).
//  - Same XCD co-location remap as proj: A panel fetched ~once per XCD.
// ---------------------------------------------------------------------------
__global__ __launch_bounds__(256, 4) void attn_out_gemm_v2(
    const unsigned char* __restrict__ A,    // (R, D) attn, values 0..4
    const unsigned short* __restrict__ WpT, // tiled split Wp
    const float*         __restrict__ bp,   // (D,)  f32
    float* __restrict__ out)                // (R, D) f32
{
    __shared__ unsigned short As[128 * 40];  // 10 KB, rows padded to 40

    const int tid  = threadIdx.x;
    const int lane = tid & 63;
    const int wsub = tid >> 6;
    const int la   = lane & 15;
    const int lq   = lane >> 4;

    const int n  = blockIdx.y * 8 + blockIdx.x;    // 0..4095
    const int bd = (n >> 3) & 7;
    const int bm = (n & 7) * 64 + (n >> 6);        // 0..511 (128-row group)

    f32x4 acc[8];
    #pragma unroll
    for (int s = 0; s < 8; s++) acc[s] = (f32x4){0.f, 0.f, 0.f, 0.f};

    // per-thread A-granule coordinates (4 granules of uchar4)
    int arow[4], akq[4];
    #pragma unroll
    for (int i = 0; i < 4; i++) {
        const int j = tid + i * 256;
        arow[i] = j >> 3;
        akq[i]  = (j & 7) * 4;
    }

    // prologue: prefetch kb=0
    uchar4 rA[4];
    #pragma unroll
    for (int i = 0; i < 4; i++)
        rA[i] = *reinterpret_cast<const uchar4*>(
            A + (size_t)(bm * 128 + arow[i]) * D_ + akq[i]);

    for (int kb = 0; kb < 16; kb++) {
        // stage current tile from regs (exact small ints -> bf16)
        #pragma unroll
        for (int i = 0; i < 4; i++) {
            ushort4 h;
            h.x = (unsigned short)(__float_as_uint((float)rA[i].x) >> 16);
            h.y = (unsigned short)(__float_as_uint((float)rA[i].y) >> 16);
            h.z = (unsigned short)(__float_as_uint((float)rA[i].z) >> 16);
            h.w = (unsigned short)(__float_as_uint((float)rA[i].w) >> 16);
            *reinterpret_cast<ushort4*>(&As[arow[i] * 40 + akq[i]]) = h;
        }
        // prefetch next tile (in flight across both barriers + compute)
        uchar4 rN[4];
        if (kb < 15) {
            #pragma unroll
            for (int i = 0; i < 4; i++)
                rN[i] = *reinterpret_cast<const uchar4*>(
                    A + (size_t)(bm * 128 + arow[i]) * D_ + (kb + 1) * 32 + akq[i]);
        }
        __syncthreads();

        // W fragments straight from tiled global (L2-hot: 128 KB per bd)
        const char* wp = (const char*)WpT + (size_t)(bd * 16 + kb) * 8192
                         + lq * 1024 + (wsub * 16 + la) * 16;
        bf16x8 bh = *reinterpret_cast<const bf16x8*>(wp);
        bf16x8 bl = *reinterpret_cast<const bf16x8*>(wp + 4096);

        #pragma unroll
        for (int s = 0; s < 8; s++) {
            bf16x8 a = *reinterpret_cast<const bf16x8*>(&As[(s * 16 + la) * 40 + lq * 8]);
            acc[s] = __builtin_amdgcn_mfma_f32_16x16x32_bf16(a, bh, acc[s], 0, 0, 0);
            acc[s] = __builtin_amdgcn_mfma_f32_16x16x32_bf16(a, bl, acc[s], 0, 0, 0);
        }
        __syncthreads();

        #pragma unroll
        for (int i = 0; i < 4; i++) rA[i] = rN[i];
    }

    const int d = bd * 64 + wsub * 16 + la;
    const float bias = bp[d];
    #pragma unroll
    for (int s = 0; s < 8; s++)
        #pragma unroll
        for (int i = 0; i < 4; i++) {
            const int m = bm * 128 + s * 16 + lq * 4 + i;
            out[(size_t)m * D_ + d] = acc[s][i] + bias;
        }
}

extern "C" void kernel_launch(void* const* d_in, const int* in_sizes, int n_in,
                              void* d_out, int out_size, void* d_ws, size_t ws_size,
                              hipStream_t stream) {
    const float* x  = (const float*)d_in[0];  // x_seq (T,B,N,D) f32
    const float* wq = (const float*)d_in[1];
    const float* wk = (const float*)d_in[2];
    const float* wv = (const float*)d_in[3];
    const float* wp = (const float*)d_in[4];
    const float* bp = (const float*)d_in[5];

    // workspace: attn 33.5M | Wt 3M | WpT 1M | Xt 128M  = 172.0 MB total
    // (rounds 2/3 proved ws_size >= 176.2 MB by taking the 176 MB fast path)
    unsigned char*  attn = (unsigned char*)d_ws;
    unsigned short* Wt   = (unsigned short*)((char*)d_ws + 33554432);
    unsigned short* WpT  = (unsigned short*)((char*)d_ws + 36700160);
    unsigned short* Xt   = (unsigned short*)((char*)d_ws + 37748736);

    dim3 blk(256);
    split_w_tiled <<<dim3(768),  blk, 0, stream>>>(wq, wk, wv, Wt);
    split_wp_tiled<<<dim3(128),  blk, 0, stream>>>(wp, WpT);
    split_x_tiled3<<<dim3(1024), blk, 0, stream>>>(x, Xt);

    dim3 g1(8, 1024);   // n = y*8+x; in-kernel XCD co-location remap
    proj_lif_attn_v4<<<g1, blk, 0, stream>>>(x, wq, wk, wv, Xt, Wt, attn);

    dim3 g2(8, 512);
    attn_out_gemm_v2<<<g2, blk, 0, stream>>>(attn, WpT, bp, (float*)d_out);
}

// Round 5
// 549.328 us; speedup vs baseline: 2.5347x; 1.0191x over previous
//
#include <hip/hip_runtime.h>
#include <hip/hip_bf16.h>
#include <stdint.h>

// Problem constants (T, B, N, D) = (4, 16, 1024, 512); M = B*N
#define T_ 4
#define M_ 16384
#define D_ 512
#define R_ (T_ * M_)    // 65536 rows total
#define EPS_TRIG 1e-4f  // ~5 sigma of the bf16-split accumulation noise

typedef short bf16x8 __attribute__((ext_vector_type(8)));   // 8 bf16 (4 VGPRs)
typedef float f32x4  __attribute__((ext_vector_type(4)));
typedef unsigned short us8 __attribute__((ext_vector_type(8)));

// x = hi + lo + residual, |residual| <= 2^-17 |x|.
static __device__ __forceinline__ void split2bf16(float x, unsigned short& h, unsigned short& l) {
    unsigned int u = __float_as_uint(x);
    h = (unsigned short)(u >> 16);
    float r = x - __uint_as_float(u & 0xFFFF0000u);   // exact
    unsigned int v = __float_as_uint(r);
    l = (unsigned short)((v + 0x7FFFu + ((v >> 16) & 1u)) >> 16);
}

// Async global->LDS, 16 B per lane. LDS dest = wave-uniform base + lane*16;
// the GLOBAL source address is per-lane.
static __device__ __forceinline__ void gload_lds16(const void* g, void* l) {
    __builtin_amdgcn_global_load_lds(
        (const __attribute__((address_space(1))) unsigned int*)g,
        (__attribute__((address_space(3))) unsigned int*)l,
        16, 0, 0);
}

// ---------------------------------------------------------------------------
// Kernel 0a: Wq/Wk/Wv split -> TILED layout (unchanged).
// Wtiled: [bd(8)][kbi(16)][wj(24)][dd(64)][16B], wj=(hl*4+g)*3+z.
// Fragment offset in 24576-B chunk: hl*12288 + g*3072 + z*1024 + dd*16.
// ---------------------------------------------------------------------------
__global__ __launch_bounds__(256) void split_w_tiled(
    const float* __restrict__ Wq, const float* __restrict__ Wk, const float* __restrict__ Wv,
    unsigned short* __restrict__ Wt)
{
    const int flat = blockIdx.x * 256 + threadIdx.x;  // 0..196607
    const int dd   = flat & 63;
    const int rest = flat >> 6;        // = bk*24 + wj
    const int wj   = rest % 24;
    const int bk   = rest / 24;        // bd*16 + kbi
    const int kbi  = bk & 15;
    const int bd   = bk >> 4;
    const int z    = wj % 3;
    const int hg   = wj / 3;
    const int hl   = hg >> 2;
    const int g    = hg & 3;

    const float* src = ((z == 0) ? Wq : (z == 1) ? Wk : Wv)
                       + (size_t)(bd * 64 + dd) * D_ + kbi * 32 + g * 8;
    float4 a = *reinterpret_cast<const float4*>(src);
    float4 b = *reinterpret_cast<const float4*>(src + 4);

    us8 hv, lv;
    unsigned short hh, ll;
    split2bf16(a.x, hh, ll); hv[0] = hh; lv[0] = ll;
    split2bf16(a.y, hh, ll); hv[1] = hh; lv[1] = ll;
    split2bf16(a.z, hh, ll); hv[2] = hh; lv[2] = ll;
    split2bf16(a.w, hh, ll); hv[3] = hh; lv[3] = ll;
    split2bf16(b.x, hh, ll); hv[4] = hh; lv[4] = ll;
    split2bf16(b.y, hh, ll); hv[5] = hh; lv[5] = ll;
    split2bf16(b.z, hh, ll); hv[6] = hh; lv[6] = ll;
    split2bf16(b.w, hh, ll); hv[7] = hh; lv[7] = ll;

    *reinterpret_cast<us8*>((char*)Wt + (size_t)flat * 16) = hl ? lv : hv;
}

// ---------------------------------------------------------------------------
// Kernel 0b: Wp split -> TILED layout (unchanged).
// WpT: per-(bd,kbi) chunk = 8192 B, layout [hl(2)][g(4)][dd(64)][16B].
// ---------------------------------------------------------------------------
__global__ __launch_bounds__(256) void split_wp_tiled(
    const float* __restrict__ Wp, unsigned short* __restrict__ WpT)
{
    const int flat = blockIdx.x * 256 + threadIdx.x;  // 0..32767
    const int dd   = flat & 63;
    const int g    = (flat >> 6) & 3;
    const int kbi  = (flat >> 8) & 15;
    const int bd   = flat >> 12;

    const float* src = Wp + (size_t)(bd * 64 + dd) * D_ + kbi * 32 + g * 8;
    float4 a = *reinterpret_cast<const float4*>(src);
    float4 b = *reinterpret_cast<const float4*>(src + 4);

    us8 hv, lv;
    unsigned short hh, ll;
    split2bf16(a.x, hh, ll); hv[0] = hh; lv[0] = ll;
    split2bf16(a.y, hh, ll); hv[1] = hh; lv[1] = ll;
    split2bf16(a.z, hh, ll); hv[2] = hh; lv[2] = ll;
    split2bf16(a.w, hh, ll); hv[3] = hh; lv[3] = ll;
    split2bf16(b.x, hh, ll); hv[4] = hh; lv[4] = ll;
    split2bf16(b.y, hh, ll); hv[5] = hh; lv[5] = ll;
    split2bf16(b.z, hh, ll); hv[6] = hh; lv[6] = ll;
    split2bf16(b.w, hh, ll); hv[7] = hh; lv[7] = ll;

    char* chunk = (char*)WpT + (size_t)(bd * 16 + kbi) * 8192;
    *reinterpret_cast<us8*>(chunk + g * 1024 + dd * 16)        = hv;
    *reinterpret_cast<us8*>(chunk + 4096 + g * 1024 + dd * 16) = lv;
}

// ---------------------------------------------------------------------------
// Kernel 0c: X split -> TILED layout (unchanged).
// Xt: per-(bmp,kbi) chunk = 8192 B, layout [hl(2)][g(4)][row'(64)][16B],
// row' = t*16 + mm, bmp = 16-row group (1024 of them).
// ---------------------------------------------------------------------------
__global__ __launch_bounds__(256) void split_x_tiled3(
    const float* __restrict__ X, unsigned short* __restrict__ Xt)
{
    const int bmp  = blockIdx.x;       // 0..1023
    const int tid  = threadIdx.x;
    const int rowp = tid >> 2;         // 0..63 = t*16+mm
    const int g    = tid & 3;
    const int t    = rowp >> 4;
    const int mm   = rowp & 15;

    const float* srow = X + (size_t)(t * M_ + bmp * 16 + mm) * D_;

    for (int kb = 0; kb < 16; kb++) {
        const float* src = srow + kb * 32 + g * 8;
        float4 a = *reinterpret_cast<const float4*>(src);
        float4 b = *reinterpret_cast<const float4*>(src + 4);

        us8 hv, lv;
        unsigned short hh, ll;
        split2bf16(a.x, hh, ll); hv[0] = hh; lv[0] = ll;
        split2bf16(a.y, hh, ll); hv[1] = hh; lv[1] = ll;
        split2bf16(a.z, hh, ll); hv[2] = hh; lv[2] = ll;
        split2bf16(a.w, hh, ll); hv[3] = hh; lv[3] = ll;
        split2bf16(b.x, hh, ll); hv[4] = hh; lv[4] = ll;
        split2bf16(b.y, hh, ll); hv[5] = hh; lv[5] = ll;
        split2bf16(b.z, hh, ll); hv[6] = hh; lv[6] = ll;
        split2bf16(b.w, hh, ll); hv[7] = hh; lv[7] = ll;

        char* chunk = (char*)Xt + (size_t)(bmp * 16 + kb) * 8192;
        *reinterpret_cast<us8*>(chunk + g * 1024 + rowp * 16)        = hv;
        *reinterpret_cast<us8*>(chunk + 4096 + g * 1024 + rowp * 16) = lv;
    }
}

// ---------------------------------------------------------------------------
// Kernel 1: projection + LIF + fixup + attn.  v5.
//
// Change vs v4 (theory: head-of-phase W-load stall): W fragments for K-step
// k+1 are prefetched into a SECOND named register set during k's MFMA phase
// (even/odd bodies, no runtime-indexed arrays). The end-of-iter barrier's
// vmcnt(0) drain now lands after the MFMA phase covered the W latency, and
// each MFMA phase starts with its W operands already in registers.
// X staging (global_load_lds, dbuf) and all numerics unchanged.
// ---------------------------------------------------------------------------
__global__ __launch_bounds__(256, 4) void proj_lif_attn_v5(
    const float* __restrict__ X,
    const float* __restrict__ Wq, const float* __restrict__ Wk, const float* __restrict__ Wv,
    const unsigned short* __restrict__ XtS, const unsigned short* __restrict__ WtS,
    unsigned char* __restrict__ attn)
{
    __shared__ unsigned short Xs[2][4096];   // 2 x 8 KB: [hl(2)][g(4)][row'(64)][16B]

    const int tid  = threadIdx.x;
    const int lane = tid & 63;
    const int wsub = tid >> 6;     // 0..3 -> 16-d subtile
    const int la   = lane & 15;
    const int lq   = lane >> 4;

    // bijective XCD co-location remap (8 XCDs, x-fastest dispatch)
    const int n   = blockIdx.y * 8 + blockIdx.x;   // 0..8191
    const int bd  = (n >> 3) & 7;
    const int bmp = (n & 7) * 128 + (n >> 6);      // 0..1023 (16-m group)

    f32x4 acc[3][T_];
    #pragma unroll
    for (int z = 0; z < 3; z++)
        #pragma unroll
        for (int t = 0; t < T_; t++)
            acc[z][t] = (f32x4){0.f, 0.f, 0.f, 0.f};

    const char* xsrc0 = (const char*)XtS + (size_t)(bmp * 16) * 8192 + wsub * 2048 + lane * 16;
    const char* wb    = (const char*)WtS + (size_t)(bd * 16) * 24576 + lq * 3072 + wsub * 256 + la * 16;
    char* xd0 = (char*)&Xs[0][0] + wsub * 2048;
    char* xd1 = (char*)&Xs[1][0] + wsub * 2048;

    bf16x8 whA[3], wlA[3], whB[3], wlB[3];

    auto loadW = [&](bf16x8 (&wh)[3], bf16x8 (&wl)[3], int kbi) {
        const char* p = wb + (size_t)kbi * 24576;
        #pragma unroll
        for (int z = 0; z < 3; z++) {
            wh[z] = *reinterpret_cast<const bf16x8*>(p + z * 1024);
            wl[z] = *reinterpret_cast<const bf16x8*>(p + z * 1024 + 12288);
        }
    };
    auto stageX = [&](int kbi, char* xd) {
        const char* xs = xsrc0 + (size_t)kbi * 8192;
        gload_lds16(xs,        xd);
        gload_lds16(xs + 1024, xd + 1024);
    };
    auto mfmaPhase = [&](const unsigned short* Xc, const bf16x8 (&wh)[3], const bf16x8 (&wl)[3]) {
        #pragma unroll
        for (int t = 0; t < T_; t++) {
            const int ab = lq * 1024 + (t * 16 + la) * 16;   // conflict-free
            bf16x8 ah = *reinterpret_cast<const bf16x8*>((const char*)Xc + ab);
            bf16x8 al = *reinterpret_cast<const bf16x8*>((const char*)Xc + 4096 + ab);
            #pragma unroll
            for (int z = 0; z < 3; z++) {
                acc[z][t] = __builtin_amdgcn_mfma_f32_16x16x32_bf16(ah, wh[z], acc[z][t], 0, 0, 0);
                acc[z][t] = __builtin_amdgcn_mfma_f32_16x16x32_bf16(ah, wl[z], acc[z][t], 0, 0, 0);
                acc[z][t] = __builtin_amdgcn_mfma_f32_16x16x32_bf16(al, wh[z], acc[z][t], 0, 0, 0);
            }
        }
    };

    // prologue: stage X(0)->buf0, W(0)->A regs
    stageX(0, xd0);
    loadW(whA, wlA, 0);
    __syncthreads();

    for (int kp = 0; kp < 8; kp++) {
        // even kbi = 2kp: prefetch X(2kp+1)->buf1, W(2kp+1)->B; MFMA buf0/A
        stageX(2 * kp + 1, xd1);
        loadW(whB, wlB, 2 * kp + 1);
        mfmaPhase(&Xs[0][0], whA, wlA);
        __syncthreads();
        // odd kbi = 2kp+1: prefetch X(2kp+2)->buf0, W(2kp+2)->A; MFMA buf1/B
        if (kp < 7) {
            stageX(2 * kp + 2, xd0);
            loadW(whA, wlA, 2 * kp + 2);
        }
        mfmaPhase(&Xs[1][0], whB, wlB);
        __syncthreads();
    }

    // Epilogue: LIF (fp32) + wave-cooperative exact-f64 fixup + attn
    const int d = bd * 64 + wsub * 16 + la;
    #pragma unroll
    for (int i = 0; i < 4; i++) {
        const int m = bmp * 16 + lq * 4 + i;
        int sp[3][T_];
        int zrisky = 0;
        #pragma unroll
        for (int z = 0; z < 3; z++) {
            float mem = 0.f;
            #pragma unroll
            for (int t = 0; t < T_; t++) {
                mem = 0.9f * mem + acc[z][t][i];
                if (fabsf(mem - 1.0f) < EPS_TRIG) zrisky |= (1 << z);
                const int sb = (mem >= 1.0f) ? 1 : 0;
                sp[z][t] = sb;
                mem -= (float)sb;
            }
        }
        unsigned long long ball = __ballot(zrisky != 0);
        while (ball) {
            const int src = (int)__builtin_ctzll(ball);
            ball &= ball - 1;
            const int bits = __shfl(zrisky, src);
            const int m_s  = bmp * 16 + (src >> 4) * 4 + i;
            const int d_s  = bd * 64 + wsub * 16 + (src & 15);
            #pragma unroll
            for (int z = 0; z < 3; z++) {
                if (!(bits & (1 << z))) continue;
                const float* Wrow = ((z == 0) ? Wq : (z == 1) ? Wk : Wv) + (size_t)d_s * D_;
                float4 w0 = *reinterpret_cast<const float4*>(Wrow + lane * 8);
                float4 w1 = *reinterpret_cast<const float4*>(Wrow + lane * 8 + 4);
                double pre[T_];
                #pragma unroll
                for (int t = 0; t < T_; t++) {
                    const float* xrow = X + (size_t)(t * M_ + m_s) * D_ + lane * 8;
                    float4 x0 = *reinterpret_cast<const float4*>(xrow);
                    float4 x1 = *reinterpret_cast<const float4*>(xrow + 4);
                    double p = (double)x0.x * (double)w0.x + (double)x0.y * (double)w0.y
                             + (double)x0.z * (double)w0.z + (double)x0.w * (double)w0.w
                             + (double)x1.x * (double)w1.x + (double)x1.y * (double)w1.y
                             + (double)x1.z * (double)w1.z + (double)x1.w * (double)w1.w;
                    #pragma unroll
                    for (int off = 32; off > 0; off >>= 1)
                        p += __shfl_xor(p, off, 64);
                    pre[t] = p;
                }
                double dm = 0.0;
                int spz[T_];
                #pragma unroll
                for (int t = 0; t < T_; t++) {
                    dm = 0.9 * dm + pre[t];
                    const int sb = (dm >= 1.0) ? 1 : 0;
                    spz[t] = sb;
                    dm -= (double)sb;
                }
                if (lane == src) {
                    #pragma unroll
                    for (int t = 0; t < T_; t++) sp[z][t] = spz[t];
                }
            }
        }
        int ctx = 0;
        #pragma unroll
        for (int t = 0; t < T_; t++) {
            ctx += sp[1][t] & sp[2][t];
            attn[(size_t)(t * M_ + m) * D_ + d] = (unsigned char)(sp[0][t] ? ctx : 0);
        }
    }
}

// ---------------------------------------------------------------------------
// Kernel 2: out = attn @ Wp^T + bp via bf16 MFMA.  v3.
//  - LDS A-tile double-buffered -> ONE barrier per K-step (store next tile
//    from prefetched regs into buf^1 while MFMA reads buf; WAR protected by
//    the previous iteration's barrier).
//  - W fragments double-buffered in registers (even/odd named sets), same
//    head-stall removal as proj v5.
//  - LDS 20 KB, ~80 VGPR -> ~6 blocks/CU for TLP over the short MFMA phase.
// ---------------------------------------------------------------------------
__global__ __launch_bounds__(256, 4) void attn_out_gemm_v3(
    const unsigned char* __restrict__ A,    // (R, D) attn, values 0..4
    const unsigned short* __restrict__ WpT, // tiled split Wp
    const float*         __restrict__ bp,   // (D,)  f32
    float* __restrict__ out)                // (R, D) f32
{
    __shared__ unsigned short As[2][128 * 40];  // 2 x 10 KB, rows padded to 40

    const int tid  = threadIdx.x;
    const int lane = tid & 63;
    const int wsub = tid >> 6;
    const int la   = lane & 15;
    const int lq   = lane >> 4;

    const int n  = blockIdx.y * 8 + blockIdx.x;    // 0..4095
    const int bd = (n >> 3) & 7;
    const int bm = (n & 7) * 64 + (n >> 6);        // 0..511 (128-row group)

    f32x4 acc[8];
    #pragma unroll
    for (int s = 0; s < 8; s++) acc[s] = (f32x4){0.f, 0.f, 0.f, 0.f};

    int arow[4], akq[4];
    #pragma unroll
    for (int i = 0; i < 4; i++) {
        const int j = tid + i * 256;
        arow[i] = j >> 3;
        akq[i]  = (j & 7) * 4;
    }
    const unsigned char* Ab = A + (size_t)(bm * 128) * D_;

    uchar4 S[4], P[4];
    bf16x8 whA, wlA, whB, wlB;

    auto loadA = [&](uchar4 (&r)[4], int kb) {
        #pragma unroll
        for (int i = 0; i < 4; i++)
            r[i] = *reinterpret_cast<const uchar4*>(
                Ab + (size_t)arow[i] * D_ + kb * 32 + akq[i]);
    };
    auto storeA = [&](int buf, const uchar4 (&r)[4]) {
        #pragma unroll
        for (int i = 0; i < 4; i++) {
            ushort4 h;
            h.x = (unsigned short)(__float_as_uint((float)r[i].x) >> 16);
            h.y = (unsigned short)(__float_as_uint((float)r[i].y) >> 16);
            h.z = (unsigned short)(__float_as_uint((float)r[i].z) >> 16);
            h.w = (unsigned short)(__float_as_uint((float)r[i].w) >> 16);
            *reinterpret_cast<ushort4*>(&As[buf][arow[i] * 40 + akq[i]]) = h;
        }
    };
    auto loadW = [&](bf16x8& wh, bf16x8& wl, int kb) {
        const char* p = (const char*)WpT + (size_t)(bd * 16 + kb) * 8192
                        + lq * 1024 + (wsub * 16 + la) * 16;
        wh = *reinterpret_cast<const bf16x8*>(p);
        wl = *reinterpret_cast<const bf16x8*>(p + 4096);
    };
    auto mfmaPhase = [&](int buf, const bf16x8& wh, const bf16x8& wl) {
        #pragma unroll
        for (int s = 0; s < 8; s++) {
            bf16x8 a = *reinterpret_cast<const bf16x8*>(&As[buf][(s * 16 + la) * 40 + lq * 8]);
            acc[s] = __builtin_amdgcn_mfma_f32_16x16x32_bf16(a, wh, acc[s], 0, 0, 0);
            acc[s] = __builtin_amdgcn_mfma_f32_16x16x32_bf16(a, wl, acc[s], 0, 0, 0);
        }
    };

    // prologue: A(0)->As[0]; W(0)->A-set; prefetch A(1)->S
    loadA(S, 0);
    storeA(0, S);
    loadW(whA, wlA, 0);
    loadA(S, 1);
    __syncthreads();

    for (int kp = 0; kp < 8; kp++) {
        // even kb = 2kp: stage S(=A(2kp+1))->As[1]; W(2kp+1)->B; prefetch A(2kp+2)->P
        storeA(1, S);
        loadW(whB, wlB, 2 * kp + 1);
        if (kp < 7) loadA(P, 2 * kp + 2);
        mfmaPhase(0, whA, wlA);
        __syncthreads();
        // odd kb = 2kp+1: stage P->As[0]; W(2kp+2)->A; prefetch A(2kp+3)->S
        if (kp < 7) {
            storeA(0, P);
            loadW(whA, wlA, 2 * kp + 2);
            loadA(S, 2 * kp + 3);
        }
        mfmaPhase(1, whB, wlB);
        __syncthreads();
    }

    const int d = bd * 64 + wsub * 16 + la;
    const float bias = bp[d];
    #pragma unroll
    for (int s = 0; s < 8; s++)
        #pragma unroll
        for (int i = 0; i < 4; i++) {
            const int m = bm * 128 + s * 16 + lq * 4 + i;
            out[(size_t)m * D_ + d] = acc[s][i] + bias;
        }
}

extern "C" void kernel_launch(void* const* d_in, const int* in_sizes, int n_in,
                              void* d_out, int out_size, void* d_ws, size_t ws_size,
                              hipStream_t stream) {
    const float* x  = (const float*)d_in[0];  // x_seq (T,B,N,D) f32
    const float* wq = (const float*)d_in[1];
    const float* wk = (const float*)d_in[2];
    const float* wv = (const float*)d_in[3];
    const float* wp = (const float*)d_in[4];
    const float* bp = (const float*)d_in[5];

    // workspace: attn 33.5M | Wt 3M | WpT 1M | Xt 128M  = 172.0 MB total
    unsigned char*  attn = (unsigned char*)d_ws;
    unsigned short* Wt   = (unsigned short*)((char*)d_ws + 33554432);
    unsigned short* WpT  = (unsigned short*)((char*)d_ws + 36700160);
    unsigned short* Xt   = (unsigned short*)((char*)d_ws + 37748736);

    dim3 blk(256);
    split_w_tiled <<<dim3(768),  blk, 0, stream>>>(wq, wk, wv, Wt);
    split_wp_tiled<<<dim3(128),  blk, 0, stream>>>(wp, WpT);
    split_x_tiled3<<<dim3(1024), blk, 0, stream>>>(x, Xt);

    dim3 g1(8, 1024);   // n = y*8+x; in-kernel XCD co-location remap
    proj_lif_attn_v5<<<g1, blk, 0, stream>>>(x, wq, wk, wv, Xt, Wt, attn);

    dim3 g2(8, 512);
    attn_out_gemm_v3<<<g2, blk, 0, stream>>>(attn, WpT, bp, (float*)d_out);
}